// Round 1
// baseline (217.876 us; speedup 1.0000x reference)
//
#include <hip/hip_runtime.h>
#include <stdint.h>

#define MAX_ITERS 20
#define EPSV 1e-7f
#define CLIPV 1e-7f
#define PI_F 3.14159265358979f
#define PIO2_F 1.57079632679490f

typedef __attribute__((ext_vector_type(8))) short short8;
typedef __attribute__((ext_vector_type(4))) float f4;

__device__ __forceinline__ f4 mfma_bf16(short8 a, short8 b, f4 c) {
    return __builtin_amdgcn_mfma_f32_16x16x32_bf16(a, b, c, 0, 0, 0);
}

// DPP-routed add: v += v[lane ^ k] within 16-lane rows, VALU pipe
template <int CTRL>
__device__ __forceinline__ float dpp_add(float v) {
    int p = __builtin_amdgcn_update_dpp(0, __float_as_int(v), CTRL, 0xF, 0xF, true);
    return v + __int_as_float(p);
}

// Sum of v over the 32 lanes of this lane's half-wave (lanes 0-31 / 32-63).
// Result is uniform within each half. xor16 hop rides the LDS crossbar
// (ds_swizzle bit-mode operates within 32-lane groups: offset 0x401F = xor 16).
__device__ __forceinline__ float halfsum32(float v) {
    v = dpp_add<0xB1>(v);   // quad_perm(1,0,3,2)  == xor1
    v = dpp_add<0x4E>(v);   // quad_perm(2,3,0,1)  == xor2
    v = dpp_add<0x141>(v);  // row_half_mirror     == xor4 (post-xor1/2 uniform 4-groups)
    v = dpp_add<0x140>(v);  // row_mirror          == xor8
    int sw = __builtin_amdgcn_ds_swizzle(__float_as_int(v), 0x401F);  // xor16 per 32-half
    return v + __int_as_float(sw);
}

__device__ __forceinline__ float bperm(int addr, int src) {
    return __int_as_float(__builtin_amdgcn_ds_bpermute(addr, src));
}

// Branchless acos, |err| ~1e-7; input pre-clipped to (-1, 1).
__device__ __forceinline__ float fast_acos(float x) {
    float a = fabsf(x);
    bool big = a > 0.5f;
    float z = big ? 0.5f * (1.0f - a) : x * x;
    float s = big ? sqrtf(z) : x;
    float p = fmaf(z, fmaf(z, fmaf(z, fmaf(z, 4.2163199048e-2f, 2.4181311049e-2f),
                                   4.5470025998e-2f), 7.4953002686e-2f),
                   1.6666752422e-1f);
    float r = fmaf(s * z, p, s);    // asin(s), |s| <= 0.5
    float big_val = (x < 0.0f) ? (PI_F - 2.0f * r) : (2.0f * r);
    return big ? big_val : (PIO2_F - r);
}

// split 8 fp32 -> truncated-bf16 hi + bf16(lo) residual
__device__ __forceinline__ void cvt_hilo(const float* v, short8& hi, short8& lo) {
#pragma unroll
    for (int i = 0; i < 8; ++i) {
        float x = v[i];
        uint32_t u = __float_as_uint(x);
        float hf = __uint_as_float(u & 0xFFFF0000u);
        float lf = x - hf;
        hi[i] = (short)(u >> 16);
        lo[i] = (short)(__float_as_uint(lf) >> 16);
    }
}

// 2 groups per wave: lanes 0-31 own group g0, lanes 32-63 own group g0+1.
// 8 groups per 256-thread block.
__global__ void __launch_bounds__(256, 4) karcher(const float* __restrict__ X,
                                                  float* __restrict__ ws,
                                                  int n_groups) {
    __shared__ float sG[8][32 * 33];   // stride-33: conflict-free row reads
    __shared__ float sPart[8];

    const int lane = threadIdx.x & 63;
    const int wid  = threadIdx.x >> 6;
    const int g0   = blockIdx.x * 8 + wid * 2;   // first of this wave's two groups
    if (threadIdx.x < 8) sPart[threadIdx.x] = 0.f;
    if (g0 >= n_groups) return;  // 8000 % 8 == 0: never diverges

    const int col  = lane & 15;
    const int quad = lane >> 4;

    // ---- Phase 1: Gram = X X^T via MFMA, hi/lo bf16 split (err ~1e-5) ------
    // Two sequential passes, one per owned group (MFMA util is ~3%: cheap).
#pragma unroll
    for (int gg = 0; gg < 2; ++gg) {
        if (g0 + gg >= n_groups) break;
        const float* Xg = X + (size_t)(g0 + gg) * (32 * 128);
        f4 acc00 = {0.f, 0.f, 0.f, 0.f};
        f4 acc01 = acc00, acc10 = acc00, acc11 = acc00;
#pragma unroll
        for (int kc = 0; kc < 4; ++kc) {
            const float* p0 = Xg + col * 128 + kc * 32 + quad * 8;
            const float* p1 = p0 + 16 * 128;
            float r0[8], r1[8];
            *(float4*)(r0)     = *(const float4*)(p0);
            *(float4*)(r0 + 4) = *(const float4*)(p0 + 4);
            *(float4*)(r1)     = *(const float4*)(p1);
            *(float4*)(r1 + 4) = *(const float4*)(p1 + 4);
            short8 H0, L0, H1, L1;
            cvt_hilo(r0, H0, L0);
            cvt_hilo(r1, H1, L1);
            acc00 = mfma_bf16(H0, H0, acc00);
            acc00 = mfma_bf16(H0, L0, acc00);
            acc00 = mfma_bf16(L0, H0, acc00);
            acc01 = mfma_bf16(H0, H1, acc01);
            acc01 = mfma_bf16(H0, L1, acc01);
            acc01 = mfma_bf16(L0, H1, acc01);
            acc10 = mfma_bf16(H1, H0, acc10);
            acc10 = mfma_bf16(H1, L0, acc10);
            acc10 = mfma_bf16(L1, H0, acc10);
            acc11 = mfma_bf16(H1, H1, acc11);
            acc11 = mfma_bf16(H1, L1, acc11);
            acc11 = mfma_bf16(L1, H1, acc11);
        }
        float* Gw = sG[wid * 2 + gg];
#pragma unroll
        for (int i = 0; i < 4; ++i) {   // C/D: col=lane&15, row=quad*4+i (G sym)
            int rw = quad * 4 + i;
            Gw[rw * 33 + col]             = acc00[i];
            Gw[rw * 33 + col + 16]        = acc01[i];
            Gw[(rw + 16) * 33 + col]      = acc10[i];
            Gw[(rw + 16) * 33 + col + 16] = acc11[i];
        }
    }
    __syncthreads();

    // ---- Phase 2: normalized Gram row into VGPRs (per-half group) ----------
    const int half = lane >> 5;
    const int r    = lane & 31;
    const float* Gh = sG[wid * 2 + half];

    // per-half broadcast addresses for ds_bpermute: lane (32*half + j), bytes.
    // Hoisted into registers once; reused every matvec iteration.
    const int bbase = (lane & 32) << 2;
    int badr[32];
#pragma unroll
    for (int j = 0; j < 32; ++j) badr[j] = bbase | (j << 2);

    float d   = Gh[r * 34];                       // diag: r*33 + r
    float inv = 1.0f / fmaxf(sqrtf(d), 1e-12f);
    const int invb = __float_as_int(inv);

    float Grow[32];
#pragma unroll
    for (int j = 0; j < 32; ++j) {
        float invj = bperm(badr[j], invb);        // inv of column j, own half
        Grow[j] = Gh[r * 33 + j] * (inv * invj);
    }

    // ---- Phase 3: mu0 = normalize(mean(Xn)) in coefficient space ------------
    float a = 1.0f / 32.0f;
    float ga;
    {
        float s0 = 0, s1 = 0, s2 = 0, s3 = 0;
#pragma unroll
        for (int j = 0; j < 8; ++j) {
            s0 += Grow[j];
            s1 += Grow[j + 8];
            s2 += Grow[j + 16];
            s3 += Grow[j + 24];
        }
        ga = ((s0 + s1) + (s2 + s3)) * (1.0f / 32.0f);
        float n2   = halfsum32(a * ga);
        float inv0 = 1.0f / fmaxf(sqrtf(n2), 1e-12f);
        a  *= inv0;
        ga *= inv0;
    }

    // ---- Phase 4: Karcher iterations in 32-dim Gram space -------------------
    for (int it = 0; it < MAX_ITERS; ++it) {
        float x  = fminf(fmaxf(ga, -1.0f + CLIPV), 1.0f - CLIPV);
        float th = fast_acos(x);
        float st = fmaxf(sqrtf(fmaxf(1.0f - x * x, 0.0f)), EPSV);
        float w  = __fdividef(th, st);
        float C  = halfsum32(w * ga);              // sum_n w_n dot_n (per half)
        float beta = (w - C * a) * (1.0f / 32.0f); // v = sum beta_n Xn_n
        const int bi = __float_as_int(beta);
        float gb0 = 0, gb1 = 0, gb2 = 0, gb3 = 0;  // (G beta)_r, 4 indep chains
#pragma unroll
        for (int j = 0; j < 8; ++j) {              // broadcasts ride the LDS pipe
            gb0 = fmaf(Grow[j],      bperm(badr[j],      bi), gb0);
            gb1 = fmaf(Grow[j + 8],  bperm(badr[j + 8],  bi), gb1);
            gb2 = fmaf(Grow[j + 16], bperm(badr[j + 16], bi), gb2);
            gb3 = fmaf(Grow[j + 24], bperm(badr[j + 24], bi), gb3);
        }
        float gb = (gb0 + gb1) + (gb2 + gb3);
        float vv = halfsum32(beta * gb);           // ||v||^2 = beta^T G beta
        float vs = fmaxf(sqrtf(fmaxf(vv, 0.0f)), EPSV);
        float cv = __cosf(vs);
        float sv = __fdividef(__sinf(vs), vs);
        a  = fmaf(sv, beta, cv * a);               // exp map (v perp mu)
        ga = fmaf(sv, gb, cv * ga);
        if (__all(vs < 1e-6f)) break;  // both halves converged; drift < 2e-5
    }

    // ---- Phase 5: per-block partial loss (NO same-address atomics) ----------
    float xf = fminf(fmaxf(ga, -1.0f + CLIPV), 1.0f - CLIPV);
    float t  = fast_acos(xf);
    float ls = halfsum32(t * t);   // per-half uniform
    if (r == 0 && (g0 + half) < n_groups) sPart[wid * 2 + half] = ls;
    __syncthreads();
    if (threadIdx.x == 0) {
        float s = 0.f;
#pragma unroll
        for (int i = 0; i < 8; ++i) s += sPart[i];
        ws[blockIdx.x] = s;
    }
}

__global__ void __launch_bounds__(256) reduce_partials(const float* __restrict__ ws,
                                                       float* __restrict__ out,
                                                       int n, float scale) {
    __shared__ float sred[4];
    float s = 0.f;
    for (int i = threadIdx.x; i < n; i += 256) s += ws[i];
#pragma unroll
    for (int m = 32; m >= 1; m >>= 1) s += __shfl_xor(s, m, 64);
    const int lane = threadIdx.x & 63, wid = threadIdx.x >> 6;
    if (lane == 0) sred[wid] = s;
    __syncthreads();
    if (threadIdx.x == 0)
        out[0] = ((sred[0] + sred[1]) + (sred[2] + sred[3])) * scale;
}

extern "C" void kernel_launch(void* const* d_in, const int* in_sizes, int n_in,
                              void* d_out, int out_size, void* d_ws, size_t ws_size,
                              hipStream_t stream) {
    const float* X = (const float*)d_in[0];
    float* out = (float*)d_out;
    float* ws = (float*)d_ws;
    int n_groups = in_sizes[0] / (32 * 128);   // 8000
    int blocks = (n_groups + 7) / 8;           // 1000 blocks, 2 groups/wave
    karcher<<<blocks, 256, 0, stream>>>(X, ws, n_groups);
    reduce_partials<<<1, 256, 0, stream>>>(ws, out, blocks, 1.0f / (float)n_groups);
}

// Round 2
// 211.017 us; speedup vs baseline: 1.0325x; 1.0325x over previous
//
#include <hip/hip_runtime.h>
#include <stdint.h>

#define MAX_ITERS 20
#define EPSV 1e-7f
#define CLIPV 1e-7f
#define PI_F 3.14159265358979f
#define PIO2_F 1.57079632679490f

typedef __attribute__((ext_vector_type(8))) short short8;
typedef __attribute__((ext_vector_type(4))) float f4;

__device__ __forceinline__ f4 mfma_bf16(short8 a, short8 b, f4 c) {
    return __builtin_amdgcn_mfma_f32_16x16x32_bf16(a, b, c, 0, 0, 0);
}

__device__ __forceinline__ float rl(float v, int l) {
    return __int_as_float(__builtin_amdgcn_readlane(__float_as_int(v), l));
}

// DPP-routed add: v += v[lane ^ k] within 16-lane rows (VALU pipe)
template <int CTRL>
__device__ __forceinline__ float dpp_add(float v) {
    int p = __builtin_amdgcn_update_dpp(0, __float_as_int(v), CTRL, 0xF, 0xF, true);
    return v + __int_as_float(p);
}
// DPP-routed move: returns v[lane ^ k] within 16-lane rows (VALU pipe)
template <int CTRL>
__device__ __forceinline__ float dpp_mov(float v) {
    return __int_as_float(__builtin_amdgcn_update_dpp(0, __float_as_int(v), CTRL, 0xF, 0xF, true));
}

// partial sum within each 16-lane row (xor1,2,4,8) — pure VALU
__device__ __forceinline__ float rowsum16(float v) {
    v = dpp_add<0xB1>(v);   // quad_perm(1,0,3,2)  == xor1
    v = dpp_add<0x4E>(v);   // quad_perm(2,3,0,1)  == xor2
    v = dpp_add<0x141>(v);  // row_half_mirror     == xor4
    v = dpp_add<0x140>(v);  // row_mirror          == xor8
    return v;
}

// per-half (32-lane) sum, result in all lanes; pure VALU (low latency)
__device__ __forceinline__ float halfsum_rl(float v, bool hB) {
    v = rowsum16(v);
    float sA = rl(v, 0) + rl(v, 16);
    float sB = rl(v, 32) + rl(v, 48);
    return hB ? sB : sA;
}

// per-half (32-lane) sum via one ds_swizzle xor16 (use where latency is hidden)
__device__ __forceinline__ float halfsum_sw(float v) {
    v = rowsum16(v);
    int sw = __builtin_amdgcn_ds_swizzle(__float_as_int(v), 0x401F);  // xor16 per 32-half
    return v + __int_as_float(sw);
}

// Branchless acos, |err| ~1e-7; input pre-clipped to (-1, 1).
__device__ __forceinline__ float fast_acos(float x) {
    float a = fabsf(x);
    bool big = a > 0.5f;
    float z = big ? 0.5f * (1.0f - a) : x * x;
    float s = big ? sqrtf(z) : x;
    float p = fmaf(z, fmaf(z, fmaf(z, fmaf(z, 4.2163199048e-2f, 2.4181311049e-2f),
                                   4.5470025998e-2f), 7.4953002686e-2f),
                   1.6666752422e-1f);
    float r = fmaf(s * z, p, s);    // asin(s), |s| <= 0.5
    float big_val = (x < 0.0f) ? (PI_F - 2.0f * r) : (2.0f * r);
    return big ? big_val : (PIO2_F - r);
}

// split 8 fp32 -> truncated-bf16 hi + bf16(lo) residual
__device__ __forceinline__ void cvt_hilo(const float* v, short8& hi, short8& lo) {
#pragma unroll
    for (int i = 0; i < 8; ++i) {
        float x = v[i];
        uint32_t u = __float_as_uint(x);
        float hf = __uint_as_float(u & 0xFFFF0000u);
        float lf = x - hf;
        hi[i] = (short)(u >> 16);
        lo[i] = (short)(__float_as_uint(lf) >> 16);
    }
}

// Gray-walk step: cur <- cur[lane^bit] (DPP), acc += Grow2[GI] * cur
#define WSTEPA(CTRL, GI) { curA = dpp_mov<CTRL>(curA); accA = fmaf(Grow2[GI], curA, accA); }
#define WSTEPB(CTRL, GI) { curB = dpp_mov<CTRL>(curB); accB = fmaf(Grow2[(GI) + 16], curB, accB); }

// 2 groups per wave: lanes 0-31 own group g0, lanes 32-63 own group g0+1.
// Iteration loop is pure-VALU cross-lane (DPP/readlane); DS ops: 2/iter.
__global__ void __launch_bounds__(256, 4) karcher(const float* __restrict__ X,
                                                  float* __restrict__ ws,
                                                  int n_groups) {
    __shared__ float sG[8][32 * 33];   // stride-33: conflict-free row reads
    __shared__ float sInv[8][32];
    __shared__ float sPart[8];

    const int lane = threadIdx.x & 63;
    const int wid  = threadIdx.x >> 6;
    const int g0   = blockIdx.x * 8 + wid * 2;   // first of this wave's two groups
    if (threadIdx.x < 8) sPart[threadIdx.x] = 0.f;
    if (g0 >= n_groups) return;  // 8000 % 8 == 0: never diverges

    const int col  = lane & 15;
    const int quad = lane >> 4;

    // ---- Phase 1: Gram = X X^T via MFMA, hi/lo bf16 split (err ~1e-5) ------
#pragma unroll
    for (int gg = 0; gg < 2; ++gg) {
        if (g0 + gg >= n_groups) break;
        const float* Xg = X + (size_t)(g0 + gg) * (32 * 128);
        f4 acc00 = {0.f, 0.f, 0.f, 0.f};
        f4 acc01 = acc00, acc10 = acc00, acc11 = acc00;
#pragma unroll
        for (int kc = 0; kc < 4; ++kc) {
            const float* p0 = Xg + col * 128 + kc * 32 + quad * 8;
            const float* p1 = p0 + 16 * 128;
            float r0[8], r1[8];
            *(float4*)(r0)     = *(const float4*)(p0);
            *(float4*)(r0 + 4) = *(const float4*)(p0 + 4);
            *(float4*)(r1)     = *(const float4*)(p1);
            *(float4*)(r1 + 4) = *(const float4*)(p1 + 4);
            short8 H0, L0, H1, L1;
            cvt_hilo(r0, H0, L0);
            cvt_hilo(r1, H1, L1);
            acc00 = mfma_bf16(H0, H0, acc00);
            acc00 = mfma_bf16(H0, L0, acc00);
            acc00 = mfma_bf16(L0, H0, acc00);
            acc01 = mfma_bf16(H0, H1, acc01);
            acc01 = mfma_bf16(H0, L1, acc01);
            acc01 = mfma_bf16(L0, H1, acc01);
            acc10 = mfma_bf16(H1, H0, acc10);
            acc10 = mfma_bf16(H1, L0, acc10);
            acc10 = mfma_bf16(L1, H0, acc10);
            acc11 = mfma_bf16(H1, H1, acc11);
            acc11 = mfma_bf16(H1, L1, acc11);
            acc11 = mfma_bf16(L1, H1, acc11);
        }
        float* Gw = sG[wid * 2 + gg];
#pragma unroll
        for (int i = 0; i < 4; ++i) {   // C/D: col=lane&15, row=quad*4+i (G sym)
            int rw = quad * 4 + i;
            Gw[rw * 33 + col]             = acc00[i];
            Gw[rw * 33 + col + 16]        = acc01[i];
            Gw[(rw + 16) * 33 + col]      = acc10[i];
            Gw[(rw + 16) * 33 + col + 16] = acc11[i];
        }
    }
    __syncthreads();

    // ---- Phase 2: xor-permuted normalized Gram row into VGPRs ---------------
    // Grow2[g] = G[r][r^g] * inv_r * inv_{r^g}: enables Gray-code DPP matvec.
    const int  half = lane >> 5;
    const bool hB   = half != 0;
    const int  r    = lane & 31;
    const float* Gh  = sG[wid * 2 + half];
    float*       siH = sInv[wid * 2 + half];

    float inv = 1.0f / fmaxf(sqrtf(Gh[r * 34]), 1e-12f);   // diag r*33+r
    siH[r] = inv;
    __syncthreads();

    float Grow2[32];
#pragma unroll
    for (int g = 0; g < 32; ++g) {
        int j = r ^ g;
        Grow2[g] = Gh[r * 33 + j] * (inv * siH[j]);
    }

    // ---- Phase 3: mu0 = normalize(mean(Xn)) in coefficient space ------------
    float a = 1.0f / 32.0f;
    float ga;
    {
        float s0 = 0, s1 = 0, s2 = 0, s3 = 0;
#pragma unroll
        for (int g = 0; g < 8; ++g) {
            s0 += Grow2[g];
            s1 += Grow2[g + 8];
            s2 += Grow2[g + 16];
            s3 += Grow2[g + 24];
        }
        ga = ((s0 + s1) + (s2 + s3)) * (1.0f / 32.0f);
        float n2   = halfsum_rl(a * ga, hB);
        float inv0 = 1.0f / fmaxf(sqrtf(n2), 1e-12f);
        a  *= inv0;
        ga *= inv0;
    }

    // ---- Phase 4: Karcher iterations, Gray-code DPP matvec ------------------
    // gw = G*w computed directly from w (no wait on C);
    // gb = (gw - C*ga)/32 since G*beta = (G*w - C*G*a)/32.
    for (int it = 0; it < MAX_ITERS; ++it) {
        float x  = fminf(fmaxf(ga, -1.0f + CLIPV), 1.0f - CLIPV);
        float th = fast_acos(x);
        float st = fmaxf(sqrtf(fmaxf(1.0f - x * x, 0.0f)), EPSV);
        float w  = __fdividef(th, st);

        // issue xor16 of w early (walk B seed); overlaps with walk A + C
        int w16i = __builtin_amdgcn_ds_swizzle(__float_as_int(w), 0x401F);

        // C = sum_n w_n dot_n (per half); latency hidden under the walks
        float C = halfsum_sw(w * ga);

        // walk A: j = r^g, g in Gray order over bits 0-3
        float curA = w;
        float accA = Grow2[0] * curA;
        WSTEPA(0xB1, 1)   WSTEPA(0x4E, 3)   WSTEPA(0xB1, 2)   WSTEPA(0x141, 6)
        WSTEPA(0xB1, 7)   WSTEPA(0x4E, 5)   WSTEPA(0xB1, 4)   WSTEPA(0x140, 12)
        WSTEPA(0xB1, 13)  WSTEPA(0x4E, 15)  WSTEPA(0xB1, 14)  WSTEPA(0x141, 10)
        WSTEPA(0xB1, 11)  WSTEPA(0x4E, 9)   WSTEPA(0xB1, 8)

        // walk B: j = r^(16+g), seeded with w[lane^16]
        float curB = __int_as_float(w16i);
        float accB = Grow2[16] * curB;
        WSTEPB(0xB1, 1)   WSTEPB(0x4E, 3)   WSTEPB(0xB1, 2)   WSTEPB(0x141, 6)
        WSTEPB(0xB1, 7)   WSTEPB(0x4E, 5)   WSTEPB(0xB1, 4)   WSTEPB(0x140, 12)
        WSTEPB(0xB1, 13)  WSTEPB(0x4E, 15)  WSTEPB(0xB1, 14)  WSTEPB(0x141, 10)
        WSTEPB(0xB1, 11)  WSTEPB(0x4E, 9)   WSTEPB(0xB1, 8)

        float gw   = accA + accB;                  // (G w)_r
        float gb   = (gw - C * ga) * (1.0f / 32.0f);
        float beta = (w  - C * a ) * (1.0f / 32.0f);

        float vv = halfsum_rl(beta * gb, hB);      // ||v||^2 = beta^T G beta
        float vs = fmaxf(sqrtf(fmaxf(vv, 0.0f)), EPSV);
        float cv = __cosf(vs);
        float sv = __fdividef(__sinf(vs), vs);
        a  = fmaf(sv, beta, cv * a);               // exp map (v perp mu)
        ga = fmaf(sv, gb, cv * ga);
        if (__all(vs < 1e-6f)) break;  // both halves converged; drift < 2e-5
    }

    // ---- Phase 5: per-block partial loss (NO same-address atomics) ----------
    float xf = fminf(fmaxf(ga, -1.0f + CLIPV), 1.0f - CLIPV);
    float t  = fast_acos(xf);
    float ls = halfsum_rl(t * t, hB);   // all lanes hold own half's value
    if (r == 0 && (g0 + half) < n_groups) sPart[wid * 2 + half] = ls;
    __syncthreads();
    if (threadIdx.x == 0) {
        float s = 0.f;
#pragma unroll
        for (int i = 0; i < 8; ++i) s += sPart[i];
        ws[blockIdx.x] = s;
    }
}

__global__ void __launch_bounds__(256) reduce_partials(const float* __restrict__ ws,
                                                       float* __restrict__ out,
                                                       int n, float scale) {
    __shared__ float sred[4];
    float s = 0.f;
    for (int i = threadIdx.x; i < n; i += 256) s += ws[i];
#pragma unroll
    for (int m = 32; m >= 1; m >>= 1) s += __shfl_xor(s, m, 64);
    const int lane = threadIdx.x & 63, wid = threadIdx.x >> 6;
    if (lane == 0) sred[wid] = s;
    __syncthreads();
    if (threadIdx.x == 0)
        out[0] = ((sred[0] + sred[1]) + (sred[2] + sred[3])) * scale;
}

extern "C" void kernel_launch(void* const* d_in, const int* in_sizes, int n_in,
                              void* d_out, int out_size, void* d_ws, size_t ws_size,
                              hipStream_t stream) {
    const float* X = (const float*)d_in[0];
    float* out = (float*)d_out;
    float* ws = (float*)d_ws;
    int n_groups = in_sizes[0] / (32 * 128);   // 8000
    int blocks = (n_groups + 7) / 8;           // 1000 blocks, 2 groups/wave
    karcher<<<blocks, 256, 0, stream>>>(X, ws, n_groups);
    reduce_partials<<<1, 256, 0, stream>>>(ws, out, blocks, 1.0f / (float)n_groups);
}